// Round 9
// baseline (323.154 us; speedup 1.0000x reference)
//
#include <hip/hip_runtime.h>
#include <math.h>

#define N_NODES 100000
#define N_EDGES 1600000
#define E_TOT   1700000   // edges + self loops
#define NEG_SLOPE 0.2f
#define SCAN_NB 98        // ceil(100000/1024)
#define G1_BLOCKS 1563    // ceil(100000/64)
#define HIST_BLOCKS 6641  // ceil(1700000/256)

typedef unsigned short ushort_t;
typedef unsigned int uint_t;

__device__ __forceinline__ float lrelu(float v) { return v > 0.f ? v : NEG_SLOPE * v; }
__device__ __forceinline__ float bf16lo(uint_t u) { return __uint_as_float(u << 16); }
__device__ __forceinline__ float bf16hi(uint_t u) { return __uint_as_float(u & 0xffff0000u); }
// f32 -> bf16 round-to-nearest-even
__device__ __forceinline__ ushort_t f2bf(float f) {
    uint_t u = __float_as_uint(f);
    u += 0x7fffu + ((u >> 16) & 1u);
    return (ushort_t)(u >> 16);
}

// ---------------- fused GEMM1 (+alpha1) || hist ----------------
// gemm1: 64 rows/block; x-tile transposed in LDS as bf16 (16 KB, one b128/k/thread).
// hist blocks: degree histogram + per-edge rank (16 KB LDS reserved -> 10 blocks/CU).
__global__ __launch_bounds__(256) void k_gemm1_hist(const float* __restrict__ x,
                                                    const float* __restrict__ W,
                                                    const float* __restrict__ a_src,
                                                    const float* __restrict__ a_dst,
                                                    ushort_t* __restrict__ hb,
                                                    float* __restrict__ as_,
                                                    float* __restrict__ ad_,
                                                    const int* __restrict__ ei,
                                                    int* __restrict__ deg,
                                                    int* __restrict__ rank)
{
    __shared__ ushort_t xT[128][64];   // 16 KB, k-major, bf16
    const int t = threadIdx.x;

    if (blockIdx.x >= G1_BLOCKS) {
        const int e = (blockIdx.x - G1_BLOCKS) * 256 + t;
        if (e < E_TOT) {
            const int d = (e < N_EDGES) ? ei[N_EDGES + e] : (e - N_EDGES);
            rank[e] = atomicAdd(&deg[d], 1);
        }
        return;
    }

    // ---- gemm1 path ----
    const int row0 = blockIdx.x * 64;
    {
        const int r = t & 63;
        const int c8 = (t >> 6) * 32;
        int rload = row0 + r;
        if (rload > N_NODES - 1) rload = N_NODES - 1;
        const float* xp = x + (size_t)rload * 128 + c8;
#pragma unroll
        for (int j = 0; j < 8; ++j) {
            const float4 v = *(const float4*)(xp + j * 4);
            const int k = c8 + j * 4;
            xT[k + 0][r] = f2bf(v.x);
            xT[k + 1][r] = f2bf(v.y);
            xT[k + 2][r] = f2bf(v.z);
            xT[k + 3][r] = f2bf(v.w);
        }
    }
    __syncthreads();

    const int cc = t & 31;
    const int rr = t >> 5;
    const int c0 = cc * 4;
    const int r0 = rr * 8;

    float4 acc[8];
#pragma unroll
    for (int i = 0; i < 8; ++i) acc[i] = make_float4(0.f, 0.f, 0.f, 0.f);

#pragma unroll 4
    for (int k = 0; k < 128; ++k) {
        const float4 w = *(const float4*)(W + k * 128 + c0);
        const uint4 u = *(const uint4*)(&xT[k][r0]);   // 8 rows, bf16
        const float x0 = bf16lo(u.x), x1 = bf16hi(u.x);
        const float x2 = bf16lo(u.y), x3 = bf16hi(u.y);
        const float x4 = bf16lo(u.z), x5 = bf16hi(u.z);
        const float x6 = bf16lo(u.w), x7 = bf16hi(u.w);
        acc[0].x = fmaf(x0, w.x, acc[0].x); acc[0].y = fmaf(x0, w.y, acc[0].y);
        acc[0].z = fmaf(x0, w.z, acc[0].z); acc[0].w = fmaf(x0, w.w, acc[0].w);
        acc[1].x = fmaf(x1, w.x, acc[1].x); acc[1].y = fmaf(x1, w.y, acc[1].y);
        acc[1].z = fmaf(x1, w.z, acc[1].z); acc[1].w = fmaf(x1, w.w, acc[1].w);
        acc[2].x = fmaf(x2, w.x, acc[2].x); acc[2].y = fmaf(x2, w.y, acc[2].y);
        acc[2].z = fmaf(x2, w.z, acc[2].z); acc[2].w = fmaf(x2, w.w, acc[2].w);
        acc[3].x = fmaf(x3, w.x, acc[3].x); acc[3].y = fmaf(x3, w.y, acc[3].y);
        acc[3].z = fmaf(x3, w.z, acc[3].z); acc[3].w = fmaf(x3, w.w, acc[3].w);
        acc[4].x = fmaf(x4, w.x, acc[4].x); acc[4].y = fmaf(x4, w.y, acc[4].y);
        acc[4].z = fmaf(x4, w.z, acc[4].z); acc[4].w = fmaf(x4, w.w, acc[4].w);
        acc[5].x = fmaf(x5, w.x, acc[5].x); acc[5].y = fmaf(x5, w.y, acc[5].y);
        acc[5].z = fmaf(x5, w.z, acc[5].z); acc[5].w = fmaf(x5, w.w, acc[5].w);
        acc[6].x = fmaf(x6, w.x, acc[6].x); acc[6].y = fmaf(x6, w.y, acc[6].y);
        acc[6].z = fmaf(x6, w.z, acc[6].z); acc[6].w = fmaf(x6, w.w, acc[6].w);
        acc[7].x = fmaf(x7, w.x, acc[7].x); acc[7].y = fmaf(x7, w.y, acc[7].y);
        acc[7].z = fmaf(x7, w.z, acc[7].z); acc[7].w = fmaf(x7, w.w, acc[7].w);
    }

    const float4 av = *(const float4*)(a_src + c0);
    const float4 bv = *(const float4*)(a_dst + c0);
    const int head = cc >> 3;
#pragma unroll
    for (int i = 0; i < 8; ++i) {
        const int r = row0 + r0 + i;
        float ps = acc[i].x * av.x + acc[i].y * av.y + acc[i].z * av.z + acc[i].w * av.w;
        float pd = acc[i].x * bv.x + acc[i].y * bv.y + acc[i].z * bv.z + acc[i].w * bv.w;
        ps += __shfl_xor(ps, 1); pd += __shfl_xor(pd, 1);
        ps += __shfl_xor(ps, 2); pd += __shfl_xor(pd, 2);
        ps += __shfl_xor(ps, 4); pd += __shfl_xor(pd, 4);
        if (r < N_NODES) {
            const uint_t p0 = f2bf(acc[i].x), p1 = f2bf(acc[i].y);
            const uint_t p2 = f2bf(acc[i].z), p3 = f2bf(acc[i].w);
            uint2 packed = make_uint2(p0 | (p1 << 16), p2 | (p3 << 16));
            *(uint2*)(hb + (size_t)r * 128 + c0) = packed;
            if ((cc & 7) == 0) { as_[r * 4 + head] = ps; ad_[r * 4 + head] = pd; }
        }
    }
}

// ---------------- CSR scan ----------------
__global__ __launch_bounds__(256) void k_scan_a(const int* __restrict__ deg, int* __restrict__ bsum)
{
    __shared__ int sd[256];
    const int b = blockIdx.x, t = threadIdx.x;
    const int base = b * 1024 + t * 4;
    int s = 0;
#pragma unroll
    for (int i = 0; i < 4; ++i) { const int idx = base + i; if (idx < N_NODES) s += deg[idx]; }
    sd[t] = s; __syncthreads();
    for (int off = 128; off > 0; off >>= 1) {
        if (t < off) sd[t] += sd[t + off];
        __syncthreads();
    }
    if (t == 0) bsum[b] = sd[0];
}

__global__ __launch_bounds__(256) void k_scan_c(const int* __restrict__ deg,
                                                const int* __restrict__ bsum,
                                                int* __restrict__ row_ptr)
{
    __shared__ int sd[256];
    __shared__ int sb[256];
    const int b = blockIdx.x, t = threadIdx.x;

    sb[t] = (t < b && t < SCAN_NB) ? bsum[t] : 0;
    __syncthreads();
    for (int off = 128; off > 0; off >>= 1) {
        if (t < off) sb[t] += sb[t + off];
        __syncthreads();
    }
    const int bscan_b = sb[0];

    const int base = b * 1024 + t * 4;
    int v0 = 0, v1 = 0, v2 = 0, v3 = 0;
    if (base + 0 < N_NODES) v0 = deg[base + 0];
    if (base + 1 < N_NODES) v1 = deg[base + 1];
    if (base + 2 < N_NODES) v2 = deg[base + 2];
    if (base + 3 < N_NODES) v3 = deg[base + 3];
    const int tot = v0 + v1 + v2 + v3;
    sd[t] = tot; __syncthreads();
    for (int off = 1; off < 256; off <<= 1) {
        int xv = 0;
        if (t >= off) xv = sd[t - off];
        __syncthreads();
        if (t >= off) sd[t] += xv;
        __syncthreads();
    }
    int run = bscan_b + sd[t] - tot;
    if (base + 0 < N_NODES) { row_ptr[base + 0] = run; run += v0; }
    if (base + 1 < N_NODES) { row_ptr[base + 1] = run; run += v1; }
    if (base + 2 < N_NODES) { row_ptr[base + 2] = run; run += v2; }
    if (base + 3 < N_NODES) { row_ptr[base + 3] = run; run += v3; }
    if (b == 0 && t == 0) row_ptr[N_NODES] = E_TOT;
}

// atomic-free fill
__global__ __launch_bounds__(256) void k_fill(const int* __restrict__ ei,
                                              const int* __restrict__ row_ptr,
                                              const int* __restrict__ rank,
                                              int* __restrict__ col_src)
{
    const int e = blockIdx.x * 256 + threadIdx.x;
    if (e >= E_TOT) return;
    int s, d;
    if (e < N_EDGES) { s = ei[e]; d = ei[N_EDGES + e]; }
    else { s = d = e - N_EDGES; }
    col_src[row_ptr[d] + rank[e]] = s;
}

// ---------------- agg1: single-pass softmax + bias + ELU -> x2[N,128] bf16 ----------------
__global__ __launch_bounds__(64) void k_agg1(const ushort_t* __restrict__ hb,
                                             const float* __restrict__ as_,
                                             const float* __restrict__ ad_,
                                             const int* __restrict__ row_ptr,
                                             const int* __restrict__ col_src,
                                             const float* __restrict__ bias,
                                             ushort_t* __restrict__ x2b)
{
    __shared__ float sEx[256];
    __shared__ int sSrc[64];
    const int n = blockIdx.x;
    const int lane = threadIdx.x;
    const int start = row_ptr[n], end = row_ptr[n + 1];
    const float4 adv = *(const float4*)(ad_ + (size_t)n * 4);

    const int hsel = lane >> 4;
    const int c0 = lane * 2;
    float2 acc = make_float2(0.f, 0.f);
    float4 ds = make_float4(0.f, 0.f, 0.f, 0.f);
    for (int base = start; base < end; base += 64) {
        const int e = base + lane;
        const int cnt = min(64, end - base);
        float4 ex = make_float4(0.f, 0.f, 0.f, 0.f);
        int s = 0;
        if (e < end) {
            s = col_src[e];
            const float4 av = *(const float4*)(as_ + (size_t)s * 4);
            ex.x = __expf(lrelu(av.x + adv.x));
            ex.y = __expf(lrelu(av.y + adv.y));
            ex.z = __expf(lrelu(av.z + adv.z));
            ex.w = __expf(lrelu(av.w + adv.w));
            ds.x += ex.x; ds.y += ex.y; ds.z += ex.z; ds.w += ex.w;
        }
        __syncthreads();
        *(float4*)(sEx + lane * 4) = ex;
        sSrc[lane] = s;
        __syncthreads();
        for (int i = 0; i < cnt; ++i) {
            const float w = sEx[i * 4 + hsel];
            const uint_t hv = *(const uint_t*)(hb + (size_t)sSrc[i] * 128 + c0);
            acc.x = fmaf(w, bf16lo(hv), acc.x);
            acc.y = fmaf(w, bf16hi(hv), acc.y);
        }
    }
#pragma unroll
    for (int off = 32; off > 0; off >>= 1) {
        ds.x += __shfl_xor(ds.x, off);
        ds.y += __shfl_xor(ds.y, off);
        ds.z += __shfl_xor(ds.z, off);
        ds.w += __shfl_xor(ds.w, off);
    }
    const float denom = hsel == 0 ? ds.x : hsel == 1 ? ds.y : hsel == 2 ? ds.z : ds.w;
    float o0 = acc.x / denom + bias[c0];
    float o1 = acc.y / denom + bias[c0 + 1];
    o0 = o0 > 0.f ? o0 : __expf(o0) - 1.f;   // ELU
    o1 = o1 > 0.f ? o1 : __expf(o1) - 1.f;
    const uint_t q0 = f2bf(o0), q1 = f2bf(o1);
    *(uint_t*)(x2b + (size_t)n * 128 + c0) = q0 | (q1 << 16);
}

// ---------------- GEMM2: 64 rows/block, W2 staged once; fused alpha2 ----------------
__global__ __launch_bounds__(256) void k_gemm2(const ushort_t* __restrict__ x2b,
                                               const float* __restrict__ W,
                                               const float* __restrict__ a_src,
                                               const float* __restrict__ a_dst,
                                               ushort_t* __restrict__ hb2,
                                               float* __restrict__ as_,
                                               float* __restrict__ ad_)
{
    __shared__ float sW[128 * 32];
    const int t = threadIdx.x;
    {
        const float4* W4 = (const float4*)W;
        float4* s4 = (float4*)sW;
#pragma unroll
        for (int i = 0; i < 4; ++i) s4[t + 256 * i] = W4[t + 256 * i];
    }
    __syncthreads();

    const int rr = t >> 5;
    const int c = t & 31;
    const float a_s = a_src[c], a_d = a_dst[c];

    for (int g = 0; g < 8; ++g) {
        const int row = blockIdx.x * 64 + g * 8 + rr;
        if (row >= N_NODES) continue;
        const ushort_t* xp = x2b + (size_t)row * 128;

        float acc = 0.f;
        for (int k = 0; k < 128; k += 4) {
            const uint2 u = *(const uint2*)(xp + k);
            acc = fmaf(bf16lo(u.x), sW[(k + 0) * 32 + c], acc);
            acc = fmaf(bf16hi(u.x), sW[(k + 1) * 32 + c], acc);
            acc = fmaf(bf16lo(u.y), sW[(k + 2) * 32 + c], acc);
            acc = fmaf(bf16hi(u.y), sW[(k + 3) * 32 + c], acc);
        }

        hb2[(size_t)row * 32 + c] = f2bf(acc);
        float ps = acc * a_s, pd = acc * a_d;
#pragma unroll
        for (int off = 16; off > 0; off >>= 1) {
            ps += __shfl_xor(ps, off);
            pd += __shfl_xor(pd, off);
        }
        if (c == 0) { as_[row] = ps; ad_[row] = pd; }
    }
}

// ---------------- agg2: single-pass softmax + bias -> out[N,32] ----------------
__global__ __launch_bounds__(64) void k_agg2(const ushort_t* __restrict__ hb2,
                                             const float* __restrict__ as_,
                                             const float* __restrict__ ad_,
                                             const int* __restrict__ row_ptr,
                                             const int* __restrict__ col_src,
                                             const float* __restrict__ bias,
                                             float* __restrict__ out)
{
    __shared__ float sEx[64];
    __shared__ int sSrc[64];
    const int n = blockIdx.x;
    const int lane = threadIdx.x;
    const int start = row_ptr[n], end = row_ptr[n + 1];
    const float adn = ad_[n];

    const int c = lane & 31, half = lane >> 5;
    float acc = 0.f, dsum = 0.f;
    for (int base = start; base < end; base += 64) {
        const int e = base + lane;
        const int cnt = min(64, end - base);
        float ex = 0.f; int s = 0;
        if (e < end) {
            s = col_src[e];
            ex = __expf(lrelu(as_[s] + adn));
            dsum += ex;
        }
        __syncthreads();
        sEx[lane] = ex;
        sSrc[lane] = s;
        __syncthreads();
        for (int i = half; i < cnt; i += 2) {
            const ushort_t u = hb2[(size_t)sSrc[i] * 32 + c];
            acc = fmaf(sEx[i], __uint_as_float((uint_t)u << 16), acc);
        }
    }
#pragma unroll
    for (int off = 32; off > 0; off >>= 1) dsum += __shfl_xor(dsum, off);
    acc += __shfl_xor(acc, 32);
    if (half == 0) out[(size_t)n * 32 + c] = acc / dsum + bias[c];
}

extern "C" void kernel_launch(void* const* d_in, const int* in_sizes, int n_in,
                              void* d_out, int out_size, void* d_ws, size_t ws_size,
                              hipStream_t stream)
{
    const float* x      = (const float*)d_in[0];
    const int*   ei     = (const int*)d_in[1];
    const float* W1     = (const float*)d_in[2];
    const float* a_src1 = (const float*)d_in[3];
    const float* a_dst1 = (const float*)d_in[4];
    const float* b1     = (const float*)d_in[5];
    const float* W2     = (const float*)d_in[6];
    const float* a_src2 = (const float*)d_in[7];
    const float* a_dst2 = (const float*)d_in[8];
    const float* b2     = (const float*)d_in[9];
    float* out = (float*)d_out;

    char* p = (char*)d_ws;
    auto alloc = [&](size_t bytes) { char* q = p; p += (bytes + 255) & ~(size_t)255; return q; };
    ushort_t* h1b = (ushort_t*)alloc((size_t)N_NODES * 128 * 2);
    ushort_t* x2b = (ushort_t*)alloc((size_t)N_NODES * 128 * 2);
    ushort_t* h2b = (ushort_t*)alloc((size_t)N_NODES * 32 * 2);
    float* as1    = (float*)alloc((size_t)N_NODES * 4 * 4);
    float* ad1    = (float*)alloc((size_t)N_NODES * 4 * 4);
    float* as2    = (float*)alloc((size_t)N_NODES * 4);
    float* ad2    = (float*)alloc((size_t)N_NODES * 4);
    int* deg      = (int*)alloc((size_t)N_NODES * 4);
    int* row_ptr  = (int*)alloc((size_t)(N_NODES + 1) * 4);
    int* rank     = (int*)alloc((size_t)E_TOT * 4);
    int* bsum     = (int*)alloc(SCAN_NB * 4);
    int* col_src  = (int*)alloc((size_t)E_TOT * 4);

    (void)hipMemsetAsync(deg, 0, (size_t)N_NODES * 4, stream);

    k_gemm1_hist<<<G1_BLOCKS + HIST_BLOCKS, 256, 0, stream>>>(
        x, W1, a_src1, a_dst1, h1b, as1, ad1, ei, deg, rank);
    k_scan_a<<<SCAN_NB, 256, 0, stream>>>(deg, bsum);
    k_scan_c<<<SCAN_NB, 256, 0, stream>>>(deg, bsum, row_ptr);
    k_fill<<<(E_TOT + 255) / 256, 256, 0, stream>>>(ei, row_ptr, rank, col_src);
    k_agg1<<<N_NODES, 64, 0, stream>>>(h1b, as1, ad1, row_ptr, col_src, b1, x2b);
    k_gemm2<<<(N_NODES + 63) / 64, 256, 0, stream>>>(x2b, W2, a_src2, a_dst2, h2b, as2, ad2);
    k_agg2<<<N_NODES, 64, 0, stream>>>(h2b, as2, ad2, row_ptr, col_src, b2, out);
}

// Round 10
// 308.667 us; speedup vs baseline: 1.0469x; 1.0469x over previous
//
#include <hip/hip_runtime.h>
#include <math.h>

#define N_NODES 100000
#define N_EDGES 1600000
#define E_TOT   1700000   // edges + self loops
#define NEG_SLOPE 0.2f
#define SCAN_NB 98        // ceil(100000/1024)
#define G1_BLOCKS 1563    // ceil(100000/64)
#define HIST_BLOCKS 6641  // ceil(1700000/256)

typedef unsigned short ushort_t;
typedef unsigned int uint_t;
typedef __attribute__((ext_vector_type(8))) short bf16x8;
typedef __attribute__((ext_vector_type(4))) float f32x4;

__device__ __forceinline__ float lrelu(float v) { return v > 0.f ? v : NEG_SLOPE * v; }
__device__ __forceinline__ float bf16lo(uint_t u) { return __uint_as_float(u << 16); }
__device__ __forceinline__ float bf16hi(uint_t u) { return __uint_as_float(u & 0xffff0000u); }
// f32 -> bf16 round-to-nearest-even
__device__ __forceinline__ ushort_t f2bf(float f) {
    uint_t u = __float_as_uint(f);
    u += 0x7fffu + ((u >> 16) & 1u);
    return (ushort_t)(u >> 16);
}

union BU { uint4 u; bf16x8 b; };

// ---------------- prep: W1 -> bf16 B-fragment layout ----------------
// Wb idx = (((kc*8 + tc)*16 + n)*4 + kq)*8 + j  maps to W[kc*32+kq*8+j][tc*16+n].
// Lane l of tile (kc,tc) then reads 16 contiguous bytes at n=l&15, kq=l>>4.
__global__ __launch_bounds__(256) void k_prep(const float* __restrict__ W,
                                              ushort_t* __restrict__ Wb)
{
    const int idx = blockIdx.x * 256 + threadIdx.x;   // 16384 total
    const int j  = idx & 7;
    const int kq = (idx >> 3) & 3;
    const int n  = (idx >> 5) & 15;
    const int tc = (idx >> 9) & 7;
    const int kc = idx >> 12;
    const int k = kc * 32 + kq * 8 + j;
    const int col = tc * 16 + n;
    Wb[idx] = f2bf(W[k * 128 + col]);
}

// ---------------- fused MFMA-GEMM1 (+alpha1) || hist ----------------
// gemm1 blocks: 64 rows/block, 4 waves x 16-row band; no LDS, no barriers.
// hist blocks: degree histogram + per-edge rank.
__global__ __launch_bounds__(256) void k_gemm1_hist(const float* __restrict__ x,
                                                    const ushort_t* __restrict__ Wb,
                                                    const float* __restrict__ a_src,
                                                    const float* __restrict__ a_dst,
                                                    ushort_t* __restrict__ hb,
                                                    float* __restrict__ as_,
                                                    float* __restrict__ ad_,
                                                    const int* __restrict__ ei,
                                                    int* __restrict__ deg,
                                                    int* __restrict__ rank)
{
    const int t = threadIdx.x;

    if (blockIdx.x >= G1_BLOCKS) {
        const int e = (blockIdx.x - G1_BLOCKS) * 256 + t;
        if (e < E_TOT) {
            const int d = (e < N_EDGES) ? ei[N_EDGES + e] : (e - N_EDGES);
            rank[e] = atomicAdd(&deg[d], 1);
        }
        return;
    }

    // ---- gemm1 path (MFMA) ----
    const int lane = t & 63;
    const int w = t >> 6;                       // wave id 0..3
    const int rbase = blockIdx.x * 64 + w * 16; // 16-row band
    const int li = lane & 15;
    const int g = lane >> 4;                    // quad group 0..3

    f32x4 acc[8];
#pragma unroll
    for (int tc = 0; tc < 8; ++tc) acc[tc] = (f32x4){0.f, 0.f, 0.f, 0.f};

    // A row for this lane (clamped for the ragged last block)
    int arow = rbase + li;
    if (arow > N_NODES - 1) arow = N_NODES - 1;
    const float* xr = x + (size_t)arow * 128 + g * 8;

#pragma unroll
    for (int kc = 0; kc < 4; ++kc) {
        // A-fragment: x[arow][kc*32 + g*8 .. +8] -> bf16x8
        const float4 a0 = *(const float4*)(xr + kc * 32);
        const float4 a1 = *(const float4*)(xr + kc * 32 + 4);
        BU au;
        au.u.x = (uint_t)f2bf(a0.x) | ((uint_t)f2bf(a0.y) << 16);
        au.u.y = (uint_t)f2bf(a0.z) | ((uint_t)f2bf(a0.w) << 16);
        au.u.z = (uint_t)f2bf(a1.x) | ((uint_t)f2bf(a1.y) << 16);
        au.u.w = (uint_t)f2bf(a1.z) | ((uint_t)f2bf(a1.w) << 16);
        const bf16x8 af = au.b;
#pragma unroll
        for (int tc = 0; tc < 8; ++tc) {
            // B-fragment: contiguous 16 B per lane
            const bf16x8 bf = *(const bf16x8*)(Wb + (size_t)(kc * 8 + tc) * 512 + li * 32 + g * 8);
            acc[tc] = __builtin_amdgcn_mfma_f32_16x16x32_bf16(af, bf, acc[tc], 0, 0, 0);
        }
    }

    // ---- epilogue: h1b stores (bf16) ----
    // D layout: col = tc*16 + li, row = rbase + g*4 + r
#pragma unroll
    for (int r = 0; r < 4; ++r) {
        const int row = rbase + g * 4 + r;
        if (row < N_NODES) {
            ushort_t* hp = hb + (size_t)row * 128 + li;
#pragma unroll
            for (int tc = 0; tc < 8; ++tc) hp[tc * 16] = f2bf(acc[tc][r]);
        }
    }

    // ---- alpha1 dots from f32 accumulators ----
    float asv[8], adv[8];
#pragma unroll
    for (int tc = 0; tc < 8; ++tc) {
        asv[tc] = a_src[tc * 16 + li];
        adv[tc] = a_dst[tc * 16 + li];
    }
#pragma unroll
    for (int h = 0; h < 4; ++h) {
#pragma unroll
        for (int r = 0; r < 4; ++r) {
            float ps = acc[2 * h][r] * asv[2 * h] + acc[2 * h + 1][r] * asv[2 * h + 1];
            float pd = acc[2 * h][r] * adv[2 * h] + acc[2 * h + 1][r] * adv[2 * h + 1];
            ps += __shfl_xor(ps, 1); pd += __shfl_xor(pd, 1);
            ps += __shfl_xor(ps, 2); pd += __shfl_xor(pd, 2);
            ps += __shfl_xor(ps, 4); pd += __shfl_xor(pd, 4);
            ps += __shfl_xor(ps, 8); pd += __shfl_xor(pd, 8);
            const int row = rbase + g * 4 + r;
            if (li == 0 && row < N_NODES) {
                as_[row * 4 + h] = ps;
                ad_[row * 4 + h] = pd;
            }
        }
    }
}

// ---------------- CSR scan ----------------
__global__ __launch_bounds__(256) void k_scan_a(const int* __restrict__ deg, int* __restrict__ bsum)
{
    __shared__ int sd[256];
    const int b = blockIdx.x, t = threadIdx.x;
    const int base = b * 1024 + t * 4;
    int s = 0;
#pragma unroll
    for (int i = 0; i < 4; ++i) { const int idx = base + i; if (idx < N_NODES) s += deg[idx]; }
    sd[t] = s; __syncthreads();
    for (int off = 128; off > 0; off >>= 1) {
        if (t < off) sd[t] += sd[t + off];
        __syncthreads();
    }
    if (t == 0) bsum[b] = sd[0];
}

__global__ __launch_bounds__(256) void k_scan_c(const int* __restrict__ deg,
                                                const int* __restrict__ bsum,
                                                int* __restrict__ row_ptr)
{
    __shared__ int sd[256];
    __shared__ int sb[256];
    const int b = blockIdx.x, t = threadIdx.x;

    sb[t] = (t < b && t < SCAN_NB) ? bsum[t] : 0;
    __syncthreads();
    for (int off = 128; off > 0; off >>= 1) {
        if (t < off) sb[t] += sb[t + off];
        __syncthreads();
    }
    const int bscan_b = sb[0];

    const int base = b * 1024 + t * 4;
    int v0 = 0, v1 = 0, v2 = 0, v3 = 0;
    if (base + 0 < N_NODES) v0 = deg[base + 0];
    if (base + 1 < N_NODES) v1 = deg[base + 1];
    if (base + 2 < N_NODES) v2 = deg[base + 2];
    if (base + 3 < N_NODES) v3 = deg[base + 3];
    const int tot = v0 + v1 + v2 + v3;
    sd[t] = tot; __syncthreads();
    for (int off = 1; off < 256; off <<= 1) {
        int xv = 0;
        if (t >= off) xv = sd[t - off];
        __syncthreads();
        if (t >= off) sd[t] += xv;
        __syncthreads();
    }
    int run = bscan_b + sd[t] - tot;
    if (base + 0 < N_NODES) { row_ptr[base + 0] = run; run += v0; }
    if (base + 1 < N_NODES) { row_ptr[base + 1] = run; run += v1; }
    if (base + 2 < N_NODES) { row_ptr[base + 2] = run; run += v2; }
    if (base + 3 < N_NODES) { row_ptr[base + 3] = run; run += v3; }
    if (b == 0 && t == 0) row_ptr[N_NODES] = E_TOT;
}

// atomic-free fill
__global__ __launch_bounds__(256) void k_fill(const int* __restrict__ ei,
                                              const int* __restrict__ row_ptr,
                                              const int* __restrict__ rank,
                                              int* __restrict__ col_src)
{
    const int e = blockIdx.x * 256 + threadIdx.x;
    if (e >= E_TOT) return;
    int s, d;
    if (e < N_EDGES) { s = ei[e]; d = ei[N_EDGES + e]; }
    else { s = d = e - N_EDGES; }
    col_src[row_ptr[d] + rank[e]] = s;
}

// ---------------- agg1: single-pass softmax + bias + ELU -> x2[N,128] bf16 ----------------
__global__ __launch_bounds__(64) void k_agg1(const ushort_t* __restrict__ hb,
                                             const float* __restrict__ as_,
                                             const float* __restrict__ ad_,
                                             const int* __restrict__ row_ptr,
                                             const int* __restrict__ col_src,
                                             const float* __restrict__ bias,
                                             ushort_t* __restrict__ x2b)
{
    __shared__ float sEx[256];
    __shared__ int sSrc[64];
    const int n = blockIdx.x;
    const int lane = threadIdx.x;
    const int start = row_ptr[n], end = row_ptr[n + 1];
    const float4 adv = *(const float4*)(ad_ + (size_t)n * 4);

    const int hsel = lane >> 4;
    const int c0 = lane * 2;
    float2 acc = make_float2(0.f, 0.f);
    float4 ds = make_float4(0.f, 0.f, 0.f, 0.f);
    for (int base = start; base < end; base += 64) {
        const int e = base + lane;
        const int cnt = min(64, end - base);
        float4 ex = make_float4(0.f, 0.f, 0.f, 0.f);
        int s = 0;
        if (e < end) {
            s = col_src[e];
            const float4 av = *(const float4*)(as_ + (size_t)s * 4);
            ex.x = __expf(lrelu(av.x + adv.x));
            ex.y = __expf(lrelu(av.y + adv.y));
            ex.z = __expf(lrelu(av.z + adv.z));
            ex.w = __expf(lrelu(av.w + adv.w));
            ds.x += ex.x; ds.y += ex.y; ds.z += ex.z; ds.w += ex.w;
        }
        __syncthreads();
        *(float4*)(sEx + lane * 4) = ex;
        sSrc[lane] = s;
        __syncthreads();
        for (int i = 0; i < cnt; ++i) {
            const float w = sEx[i * 4 + hsel];
            const uint_t hv = *(const uint_t*)(hb + (size_t)sSrc[i] * 128 + c0);
            acc.x = fmaf(w, bf16lo(hv), acc.x);
            acc.y = fmaf(w, bf16hi(hv), acc.y);
        }
    }
#pragma unroll
    for (int off = 32; off > 0; off >>= 1) {
        ds.x += __shfl_xor(ds.x, off);
        ds.y += __shfl_xor(ds.y, off);
        ds.z += __shfl_xor(ds.z, off);
        ds.w += __shfl_xor(ds.w, off);
    }
    const float denom = hsel == 0 ? ds.x : hsel == 1 ? ds.y : hsel == 2 ? ds.z : ds.w;
    float o0 = acc.x / denom + bias[c0];
    float o1 = acc.y / denom + bias[c0 + 1];
    o0 = o0 > 0.f ? o0 : __expf(o0) - 1.f;   // ELU
    o1 = o1 > 0.f ? o1 : __expf(o1) - 1.f;
    const uint_t q0 = f2bf(o0), q1 = f2bf(o1);
    *(uint_t*)(x2b + (size_t)n * 128 + c0) = q0 | (q1 << 16);
}

// ---------------- GEMM2: 64 rows/block, W2 staged once; fused alpha2 ----------------
__global__ __launch_bounds__(256) void k_gemm2(const ushort_t* __restrict__ x2b,
                                               const float* __restrict__ W,
                                               const float* __restrict__ a_src,
                                               const float* __restrict__ a_dst,
                                               ushort_t* __restrict__ hb2,
                                               float* __restrict__ as_,
                                               float* __restrict__ ad_)
{
    __shared__ float sW[128 * 32];
    const int t = threadIdx.x;
    {
        const float4* W4 = (const float4*)W;
        float4* s4 = (float4*)sW;
#pragma unroll
        for (int i = 0; i < 4; ++i) s4[t + 256 * i] = W4[t + 256 * i];
    }
    __syncthreads();

    const int rr = t >> 5;
    const int c = t & 31;
    const float a_s = a_src[c], a_d = a_dst[c];

    for (int g = 0; g < 8; ++g) {
        const int row = blockIdx.x * 64 + g * 8 + rr;
        if (row >= N_NODES) continue;
        const ushort_t* xp = x2b + (size_t)row * 128;

        float acc = 0.f;
        for (int k = 0; k < 128; k += 4) {
            const uint2 u = *(const uint2*)(xp + k);
            acc = fmaf(bf16lo(u.x), sW[(k + 0) * 32 + c], acc);
            acc = fmaf(bf16hi(u.x), sW[(k + 1) * 32 + c], acc);
            acc = fmaf(bf16lo(u.y), sW[(k + 2) * 32 + c], acc);
            acc = fmaf(bf16hi(u.y), sW[(k + 3) * 32 + c], acc);
        }

        hb2[(size_t)row * 32 + c] = f2bf(acc);
        float ps = acc * a_s, pd = acc * a_d;
#pragma unroll
        for (int off = 16; off > 0; off >>= 1) {
            ps += __shfl_xor(ps, off);
            pd += __shfl_xor(pd, off);
        }
        if (c == 0) { as_[row] = ps; ad_[row] = pd; }
    }
}

// ---------------- agg2: single-pass softmax + bias -> out[N,32] ----------------
__global__ __launch_bounds__(64) void k_agg2(const ushort_t* __restrict__ hb2,
                                             const float* __restrict__ as_,
                                             const float* __restrict__ ad_,
                                             const int* __restrict__ row_ptr,
                                             const int* __restrict__ col_src,
                                             const float* __restrict__ bias,
                                             float* __restrict__ out)
{
    __shared__ float sEx[64];
    __shared__ int sSrc[64];
    const int n = blockIdx.x;
    const int lane = threadIdx.x;
    const int start = row_ptr[n], end = row_ptr[n + 1];
    const float adn = ad_[n];

    const int c = lane & 31, half = lane >> 5;
    float acc = 0.f, dsum = 0.f;
    for (int base = start; base < end; base += 64) {
        const int e = base + lane;
        const int cnt = min(64, end - base);
        float ex = 0.f; int s = 0;
        if (e < end) {
            s = col_src[e];
            ex = __expf(lrelu(as_[s] + adn));
            dsum += ex;
        }
        __syncthreads();
        sEx[lane] = ex;
        sSrc[lane] = s;
        __syncthreads();
        for (int i = half; i < cnt; i += 2) {
            const ushort_t u = hb2[(size_t)sSrc[i] * 32 + c];
            acc = fmaf(sEx[i], __uint_as_float((uint_t)u << 16), acc);
        }
    }
#pragma unroll
    for (int off = 32; off > 0; off >>= 1) dsum += __shfl_xor(dsum, off);
    acc += __shfl_xor(acc, 32);
    if (half == 0) out[(size_t)n * 32 + c] = acc / dsum + bias[c];
}

extern "C" void kernel_launch(void* const* d_in, const int* in_sizes, int n_in,
                              void* d_out, int out_size, void* d_ws, size_t ws_size,
                              hipStream_t stream)
{
    const float* x      = (const float*)d_in[0];
    const int*   ei     = (const int*)d_in[1];
    const float* W1     = (const float*)d_in[2];
    const float* a_src1 = (const float*)d_in[3];
    const float* a_dst1 = (const float*)d_in[4];
    const float* b1     = (const float*)d_in[5];
    const float* W2     = (const float*)d_in[6];
    const float* a_src2 = (const float*)d_in[7];
    const float* a_dst2 = (const float*)d_in[8];
    const float* b2     = (const float*)d_in[9];
    float* out = (float*)d_out;

    char* p = (char*)d_ws;
    auto alloc = [&](size_t bytes) { char* q = p; p += (bytes + 255) & ~(size_t)255; return q; };
    ushort_t* h1b = (ushort_t*)alloc((size_t)N_NODES * 128 * 2);
    ushort_t* x2b = (ushort_t*)alloc((size_t)N_NODES * 128 * 2);
    ushort_t* h2b = (ushort_t*)alloc((size_t)N_NODES * 32 * 2);
    ushort_t* Wb  = (ushort_t*)alloc((size_t)16384 * 2);
    float* as1    = (float*)alloc((size_t)N_NODES * 4 * 4);
    float* ad1    = (float*)alloc((size_t)N_NODES * 4 * 4);
    float* as2    = (float*)alloc((size_t)N_NODES * 4);
    float* ad2    = (float*)alloc((size_t)N_NODES * 4);
    int* deg      = (int*)alloc((size_t)N_NODES * 4);
    int* row_ptr  = (int*)alloc((size_t)(N_NODES + 1) * 4);
    int* rank     = (int*)alloc((size_t)E_TOT * 4);
    int* bsum     = (int*)alloc(SCAN_NB * 4);
    int* col_src  = (int*)alloc((size_t)E_TOT * 4);

    (void)hipMemsetAsync(deg, 0, (size_t)N_NODES * 4, stream);

    k_prep<<<64, 256, 0, stream>>>(W1, Wb);
    k_gemm1_hist<<<G1_BLOCKS + HIST_BLOCKS, 256, 0, stream>>>(
        x, Wb, a_src1, a_dst1, h1b, as1, ad1, ei, deg, rank);
    k_scan_a<<<SCAN_NB, 256, 0, stream>>>(deg, bsum);
    k_scan_c<<<SCAN_NB, 256, 0, stream>>>(deg, bsum, row_ptr);
    k_fill<<<(E_TOT + 255) / 256, 256, 0, stream>>>(ei, row_ptr, rank, col_src);
    k_agg1<<<N_NODES, 64, 0, stream>>>(h1b, as1, ad1, row_ptr, col_src, b1, x2b);
    k_gemm2<<<(N_NODES + 63) / 64, 256, 0, stream>>>(x2b, W2, a_src2, a_dst2, h2b, as2, ad2);
    k_agg2<<<N_NODES, 64, 0, stream>>>(h2b, as2, ad2, row_ptr, col_src, b2, out);
}

// Round 11
// 273.128 us; speedup vs baseline: 1.1832x; 1.1301x over previous
//
#include <hip/hip_runtime.h>
#include <math.h>

#define N_NODES 100000
#define N_EDGES 1600000
#define E_TOT   1700000   // edges + self loops
#define NEG_SLOPE 0.2f
#define NBUCK 196         // ceil(100000/512) coarse buckets (dst>>9)
#define G1_BLOCKS 1563    // ceil(100000/64)
#define HISTB_BLOCKS 831  // ceil(1700000/2048)

typedef unsigned short ushort_t;
typedef unsigned int uint_t;
typedef __attribute__((ext_vector_type(8))) short bf16x8;
typedef __attribute__((ext_vector_type(4))) float f32x4;

__device__ __forceinline__ float lrelu(float v) { return v > 0.f ? v : NEG_SLOPE * v; }
__device__ __forceinline__ float bf16lo(uint_t u) { return __uint_as_float(u << 16); }
__device__ __forceinline__ float bf16hi(uint_t u) { return __uint_as_float(u & 0xffff0000u); }
// f32 -> bf16 round-to-nearest-even
__device__ __forceinline__ ushort_t f2bf(float f) {
    uint_t u = __float_as_uint(f);
    u += 0x7fffu + ((u >> 16) & 1u);
    return (ushort_t)(u >> 16);
}

union BU { uint4 u; bf16x8 b; };

// ---------------- prep: W1 -> bf16 B-fragment layout; zero bucket_cnt ----------------
__global__ __launch_bounds__(256) void k_prep(const float* __restrict__ W,
                                              ushort_t* __restrict__ Wb,
                                              int* __restrict__ bucket_cnt)
{
    const int idx = blockIdx.x * 256 + threadIdx.x;   // 16384 total
    if (blockIdx.x == 0 && threadIdx.x <= NBUCK) bucket_cnt[threadIdx.x] = 0;
    const int j  = idx & 7;
    const int kq = (idx >> 3) & 3;
    const int n  = (idx >> 5) & 15;
    const int tc = (idx >> 9) & 7;
    const int kc = idx >> 12;
    const int k = kc * 32 + kq * 8 + j;
    const int col = tc * 16 + n;
    Wb[idx] = f2bf(W[k * 128 + col]);
}

// ---------------- fused MFMA-GEMM1 (+alpha1) || coarse bucket histogram ----------------
__global__ __launch_bounds__(256) void k_gemm1_histB(const float* __restrict__ x,
                                                     const ushort_t* __restrict__ Wb,
                                                     const float* __restrict__ a_src,
                                                     const float* __restrict__ a_dst,
                                                     ushort_t* __restrict__ hb,
                                                     float* __restrict__ as_,
                                                     float* __restrict__ ad_,
                                                     const int* __restrict__ ei,
                                                     int* __restrict__ bucket_cnt)
{
    __shared__ int lbin[NBUCK];
    const int t = threadIdx.x;

    if (blockIdx.x >= G1_BLOCKS) {
        // ---- coarse histogram path ----
        const int e0 = (blockIdx.x - G1_BLOCKS) * 2048 + t;
        for (int i = t; i < NBUCK; i += 256) lbin[i] = 0;
        __syncthreads();
#pragma unroll
        for (int i = 0; i < 8; ++i) {
            const int e = e0 + i * 256;
            if (e < E_TOT) {
                const int d = (e < N_EDGES) ? ei[N_EDGES + e] : (e - N_EDGES);
                atomicAdd(&lbin[d >> 9], 1);
            }
        }
        __syncthreads();
        for (int i = t; i < NBUCK; i += 256)
            if (lbin[i]) atomicAdd(&bucket_cnt[i], lbin[i]);
        return;
    }

    // ---- gemm1 path (MFMA) ----
    const int lane = t & 63;
    const int w = t >> 6;
    const int rbase = blockIdx.x * 64 + w * 16;
    const int li = lane & 15;
    const int g = lane >> 4;

    f32x4 acc[8];
#pragma unroll
    for (int tc = 0; tc < 8; ++tc) acc[tc] = (f32x4){0.f, 0.f, 0.f, 0.f};

    int arow = rbase + li;
    if (arow > N_NODES - 1) arow = N_NODES - 1;
    const float* xr = x + (size_t)arow * 128 + g * 8;

#pragma unroll
    for (int kc = 0; kc < 4; ++kc) {
        const float4 a0 = *(const float4*)(xr + kc * 32);
        const float4 a1 = *(const float4*)(xr + kc * 32 + 4);
        BU au;
        au.u.x = (uint_t)f2bf(a0.x) | ((uint_t)f2bf(a0.y) << 16);
        au.u.y = (uint_t)f2bf(a0.z) | ((uint_t)f2bf(a0.w) << 16);
        au.u.z = (uint_t)f2bf(a1.x) | ((uint_t)f2bf(a1.y) << 16);
        au.u.w = (uint_t)f2bf(a1.z) | ((uint_t)f2bf(a1.w) << 16);
        const bf16x8 af = au.b;
#pragma unroll
        for (int tc = 0; tc < 8; ++tc) {
            const bf16x8 bf = *(const bf16x8*)(Wb + (size_t)(kc * 8 + tc) * 512 + li * 32 + g * 8);
            acc[tc] = __builtin_amdgcn_mfma_f32_16x16x32_bf16(af, bf, acc[tc], 0, 0, 0);
        }
    }

#pragma unroll
    for (int r = 0; r < 4; ++r) {
        const int row = rbase + g * 4 + r;
        if (row < N_NODES) {
            ushort_t* hp = hb + (size_t)row * 128 + li;
#pragma unroll
            for (int tc = 0; tc < 8; ++tc) hp[tc * 16] = f2bf(acc[tc][r]);
        }
    }

    float asv[8], adv[8];
#pragma unroll
    for (int tc = 0; tc < 8; ++tc) {
        asv[tc] = a_src[tc * 16 + li];
        adv[tc] = a_dst[tc * 16 + li];
    }
#pragma unroll
    for (int h = 0; h < 4; ++h) {
#pragma unroll
        for (int r = 0; r < 4; ++r) {
            float ps = acc[2 * h][r] * asv[2 * h] + acc[2 * h + 1][r] * asv[2 * h + 1];
            float pd = acc[2 * h][r] * adv[2 * h] + acc[2 * h + 1][r] * adv[2 * h + 1];
            ps += __shfl_xor(ps, 1); pd += __shfl_xor(pd, 1);
            ps += __shfl_xor(ps, 2); pd += __shfl_xor(pd, 2);
            ps += __shfl_xor(ps, 4); pd += __shfl_xor(pd, 4);
            ps += __shfl_xor(ps, 8); pd += __shfl_xor(pd, 8);
            const int row = rbase + g * 4 + r;
            if (li == 0 && row < N_NODES) {
                as_[row * 4 + h] = ps;
                ad_[row * 4 + h] = pd;
            }
        }
    }
}

// ---------------- scanB: exclusive scan of bucket counts; init cursors ----------------
__global__ __launch_bounds__(256) void k_scanB(const int* __restrict__ bucket_cnt,
                                               int* __restrict__ bucket_base,
                                               int* __restrict__ bucket_cursor)
{
    __shared__ int s[256];
    const int t = threadIdx.x;
    const int v = (t < NBUCK) ? bucket_cnt[t] : 0;
    s[t] = v; __syncthreads();
    for (int off = 1; off < 256; off <<= 1) {
        int a = (t >= off) ? s[t - off] : 0;
        __syncthreads();
        s[t] += a;
        __syncthreads();
    }
    const int excl = s[t] - v;
    if (t < NBUCK) {
        bucket_base[t] = excl;
        bucket_cursor[t] = excl;
        if (t == NBUCK - 1) bucket_base[NBUCK] = excl + v;
    }
}

// ---------------- scatterB: edges -> bucket-grouped (src,dst) pairs ----------------
__global__ __launch_bounds__(256) void k_scatterB(const int* __restrict__ ei,
                                                  int* __restrict__ bucket_cursor,
                                                  uint2* __restrict__ pairs)
{
    __shared__ int lcnt[NBUCK];
    __shared__ int lbase[NBUCK];
    const int t = threadIdx.x;
    const int e0 = blockIdx.x * 2048 + t;

    for (int i = t; i < NBUCK; i += 256) lcnt[i] = 0;
    __syncthreads();

    int s8[8], d8[8];
#pragma unroll
    for (int i = 0; i < 8; ++i) {
        const int e = e0 + i * 256;
        int s = -1, d = 0;
        if (e < E_TOT) {
            if (e < N_EDGES) { s = ei[e]; d = ei[N_EDGES + e]; }
            else { s = d = e - N_EDGES; }
            atomicAdd(&lcnt[d >> 9], 1);
        }
        s8[i] = s; d8[i] = d;
    }
    __syncthreads();
    for (int i = t; i < NBUCK; i += 256) {
        const int c = lcnt[i];
        lbase[i] = (c > 0) ? atomicAdd(&bucket_cursor[i], c) : 0;
    }
    __syncthreads();
    for (int i = t; i < NBUCK; i += 256) lcnt[i] = 0;   // reuse as local cursor
    __syncthreads();
#pragma unroll
    for (int i = 0; i < 8; ++i) {
        if (s8[i] >= 0) {
            const int b = d8[i] >> 9;
            const int pos = lbase[b] + atomicAdd(&lcnt[b], 1);
            pairs[pos] = make_uint2((uint_t)s8[i], (uint_t)d8[i]);
        }
    }
}

// ---------------- buildC: per-bucket fine sort -> row_ptr + col_src ----------------
__global__ __launch_bounds__(256) void k_buildC(const uint2* __restrict__ pairs,
                                                const int* __restrict__ bucket_base,
                                                int* __restrict__ row_ptr,
                                                int* __restrict__ col_src)
{
    __shared__ int cnt[512];
    __shared__ int cur[512];
    __shared__ int ps[256];
    const int b = blockIdx.x, t = threadIdx.x;
    const int bstart = bucket_base[b], bend = bucket_base[b + 1];
    const int node0 = b << 9;

    cnt[t] = 0; cnt[t + 256] = 0;
    __syncthreads();
    for (int e = bstart + t; e < bend; e += 256)
        atomicAdd(&cnt[pairs[e].y - node0], 1);
    __syncthreads();

    const int pa = cnt[2 * t], pb = cnt[2 * t + 1];
    ps[t] = pa + pb; __syncthreads();
    for (int off = 1; off < 256; off <<= 1) {
        int a = (t >= off) ? ps[t - off] : 0;
        __syncthreads();
        ps[t] += a;
        __syncthreads();
    }
    const int pe = bstart + ps[t] - (pa + pb);   // exclusive base for bin 2t
    cur[2 * t] = pe;
    cur[2 * t + 1] = pe + pa;
    const int n0 = node0 + 2 * t, n1 = node0 + 2 * t + 1;
    if (n0 < N_NODES) row_ptr[n0] = pe;
    if (n1 < N_NODES) row_ptr[n1] = pe + pa;
    if (b == 0 && t == 0) row_ptr[N_NODES] = E_TOT;
    __syncthreads();

    for (int e = bstart + t; e < bend; e += 256) {
        const uint2 pr = pairs[e];
        const int pos = atomicAdd(&cur[pr.y - node0], 1);
        col_src[pos] = (int)pr.x;
    }
}

// ---------------- agg1: single-pass softmax + bias + ELU -> x2[N,128] bf16 ----------------
__global__ __launch_bounds__(64) void k_agg1(const ushort_t* __restrict__ hb,
                                             const float* __restrict__ as_,
                                             const float* __restrict__ ad_,
                                             const int* __restrict__ row_ptr,
                                             const int* __restrict__ col_src,
                                             const float* __restrict__ bias,
                                             ushort_t* __restrict__ x2b)
{
    __shared__ float sEx[256];
    __shared__ int sSrc[64];
    const int n = blockIdx.x;
    const int lane = threadIdx.x;
    const int start = row_ptr[n], end = row_ptr[n + 1];
    const float4 adv = *(const float4*)(ad_ + (size_t)n * 4);

    const int hsel = lane >> 4;
    const int c0 = lane * 2;
    float2 acc = make_float2(0.f, 0.f);
    float4 ds = make_float4(0.f, 0.f, 0.f, 0.f);
    for (int base = start; base < end; base += 64) {
        const int e = base + lane;
        const int cnt = min(64, end - base);
        float4 ex = make_float4(0.f, 0.f, 0.f, 0.f);
        int s = 0;
        if (e < end) {
            s = col_src[e];
            const float4 av = *(const float4*)(as_ + (size_t)s * 4);
            ex.x = __expf(lrelu(av.x + adv.x));
            ex.y = __expf(lrelu(av.y + adv.y));
            ex.z = __expf(lrelu(av.z + adv.z));
            ex.w = __expf(lrelu(av.w + adv.w));
            ds.x += ex.x; ds.y += ex.y; ds.z += ex.z; ds.w += ex.w;
        }
        __syncthreads();
        *(float4*)(sEx + lane * 4) = ex;
        sSrc[lane] = s;
        __syncthreads();
        for (int i = 0; i < cnt; ++i) {
            const float w = sEx[i * 4 + hsel];
            const uint_t hv = *(const uint_t*)(hb + (size_t)sSrc[i] * 128 + c0);
            acc.x = fmaf(w, bf16lo(hv), acc.x);
            acc.y = fmaf(w, bf16hi(hv), acc.y);
        }
    }
#pragma unroll
    for (int off = 32; off > 0; off >>= 1) {
        ds.x += __shfl_xor(ds.x, off);
        ds.y += __shfl_xor(ds.y, off);
        ds.z += __shfl_xor(ds.z, off);
        ds.w += __shfl_xor(ds.w, off);
    }
    const float denom = hsel == 0 ? ds.x : hsel == 1 ? ds.y : hsel == 2 ? ds.z : ds.w;
    float o0 = acc.x / denom + bias[c0];
    float o1 = acc.y / denom + bias[c0 + 1];
    o0 = o0 > 0.f ? o0 : __expf(o0) - 1.f;   // ELU
    o1 = o1 > 0.f ? o1 : __expf(o1) - 1.f;
    const uint_t q0 = f2bf(o0), q1 = f2bf(o1);
    *(uint_t*)(x2b + (size_t)n * 128 + c0) = q0 | (q1 << 16);
}

// ---------------- GEMM2: 64 rows/block, W2 staged once; fused alpha2 ----------------
__global__ __launch_bounds__(256) void k_gemm2(const ushort_t* __restrict__ x2b,
                                               const float* __restrict__ W,
                                               const float* __restrict__ a_src,
                                               const float* __restrict__ a_dst,
                                               ushort_t* __restrict__ hb2,
                                               float* __restrict__ as_,
                                               float* __restrict__ ad_)
{
    __shared__ float sW[128 * 32];
    const int t = threadIdx.x;
    {
        const float4* W4 = (const float4*)W;
        float4* s4 = (float4*)sW;
#pragma unroll
        for (int i = 0; i < 4; ++i) s4[t + 256 * i] = W4[t + 256 * i];
    }
    __syncthreads();

    const int rr = t >> 5;
    const int c = t & 31;
    const float a_s = a_src[c], a_d = a_dst[c];

    for (int g = 0; g < 8; ++g) {
        const int row = blockIdx.x * 64 + g * 8 + rr;
        if (row >= N_NODES) continue;
        const ushort_t* xp = x2b + (size_t)row * 128;

        float acc = 0.f;
        for (int k = 0; k < 128; k += 4) {
            const uint2 u = *(const uint2*)(xp + k);
            acc = fmaf(bf16lo(u.x), sW[(k + 0) * 32 + c], acc);
            acc = fmaf(bf16hi(u.x), sW[(k + 1) * 32 + c], acc);
            acc = fmaf(bf16lo(u.y), sW[(k + 2) * 32 + c], acc);
            acc = fmaf(bf16hi(u.y), sW[(k + 3) * 32 + c], acc);
        }

        hb2[(size_t)row * 32 + c] = f2bf(acc);
        float ps = acc * a_s, pd = acc * a_d;
#pragma unroll
        for (int off = 16; off > 0; off >>= 1) {
            ps += __shfl_xor(ps, off);
            pd += __shfl_xor(pd, off);
        }
        if (c == 0) { as_[row] = ps; ad_[row] = pd; }
    }
}

// ---------------- agg2: single-pass softmax + bias -> out[N,32] ----------------
__global__ __launch_bounds__(64) void k_agg2(const ushort_t* __restrict__ hb2,
                                             const float* __restrict__ as_,
                                             const float* __restrict__ ad_,
                                             const int* __restrict__ row_ptr,
                                             const int* __restrict__ col_src,
                                             const float* __restrict__ bias,
                                             float* __restrict__ out)
{
    __shared__ float sEx[64];
    __shared__ int sSrc[64];
    const int n = blockIdx.x;
    const int lane = threadIdx.x;
    const int start = row_ptr[n], end = row_ptr[n + 1];
    const float adn = ad_[n];

    const int c = lane & 31, half = lane >> 5;
    float acc = 0.f, dsum = 0.f;
    for (int base = start; base < end; base += 64) {
        const int e = base + lane;
        const int cnt = min(64, end - base);
        float ex = 0.f; int s = 0;
        if (e < end) {
            s = col_src[e];
            ex = __expf(lrelu(as_[s] + adn));
            dsum += ex;
        }
        __syncthreads();
        sEx[lane] = ex;
        sSrc[lane] = s;
        __syncthreads();
        for (int i = half; i < cnt; i += 2) {
            const ushort_t u = hb2[(size_t)sSrc[i] * 32 + c];
            acc = fmaf(sEx[i], __uint_as_float((uint_t)u << 16), acc);
        }
    }
#pragma unroll
    for (int off = 32; off > 0; off >>= 1) dsum += __shfl_xor(dsum, off);
    acc += __shfl_xor(acc, 32);
    if (half == 0) out[(size_t)n * 32 + c] = acc / dsum + bias[c];
}

extern "C" void kernel_launch(void* const* d_in, const int* in_sizes, int n_in,
                              void* d_out, int out_size, void* d_ws, size_t ws_size,
                              hipStream_t stream)
{
    const float* x      = (const float*)d_in[0];
    const int*   ei     = (const int*)d_in[1];
    const float* W1     = (const float*)d_in[2];
    const float* a_src1 = (const float*)d_in[3];
    const float* a_dst1 = (const float*)d_in[4];
    const float* b1     = (const float*)d_in[5];
    const float* W2     = (const float*)d_in[6];
    const float* a_src2 = (const float*)d_in[7];
    const float* a_dst2 = (const float*)d_in[8];
    const float* b2     = (const float*)d_in[9];
    float* out = (float*)d_out;

    char* p = (char*)d_ws;
    auto alloc = [&](size_t bytes) { char* q = p; p += (bytes + 255) & ~(size_t)255; return q; };
    ushort_t* h1b = (ushort_t*)alloc((size_t)N_NODES * 128 * 2);
    ushort_t* x2b = (ushort_t*)alloc((size_t)N_NODES * 128 * 2);
    ushort_t* h2b = (ushort_t*)alloc((size_t)N_NODES * 32 * 2);
    ushort_t* Wb  = (ushort_t*)alloc((size_t)16384 * 2);
    float* as1    = (float*)alloc((size_t)N_NODES * 4 * 4);
    float* ad1    = (float*)alloc((size_t)N_NODES * 4 * 4);
    float* as2    = (float*)alloc((size_t)N_NODES * 4);
    float* ad2    = (float*)alloc((size_t)N_NODES * 4);
    int* row_ptr  = (int*)alloc((size_t)(N_NODES + 1) * 4);
    int* bucket_cnt    = (int*)alloc((NBUCK + 1) * 4);
    int* bucket_base   = (int*)alloc((NBUCK + 1) * 4);
    int* bucket_cursor = (int*)alloc((NBUCK + 1) * 4);
    uint2* pairs  = (uint2*)alloc((size_t)E_TOT * 8);
    int* col_src  = (int*)alloc((size_t)E_TOT * 4);

    k_prep<<<64, 256, 0, stream>>>(W1, Wb, bucket_cnt);
    k_gemm1_histB<<<G1_BLOCKS + HISTB_BLOCKS, 256, 0, stream>>>(
        x, Wb, a_src1, a_dst1, h1b, as1, ad1, ei, bucket_cnt);
    k_scanB<<<1, 256, 0, stream>>>(bucket_cnt, bucket_base, bucket_cursor);
    k_scatterB<<<HISTB_BLOCKS, 256, 0, stream>>>(ei, bucket_cursor, pairs);
    k_buildC<<<NBUCK, 256, 0, stream>>>(pairs, bucket_base, row_ptr, col_src);
    k_agg1<<<N_NODES, 64, 0, stream>>>(h1b, as1, ad1, row_ptr, col_src, b1, x2b);
    k_gemm2<<<(N_NODES + 63) / 64, 256, 0, stream>>>(x2b, W2, a_src2, a_dst2, h2b, as2, ad2);
    k_agg2<<<N_NODES, 64, 0, stream>>>(h2b, as2, ad2, row_ptr, col_src, b2, out);
}

// Round 12
// 265.132 us; speedup vs baseline: 1.2188x; 1.0302x over previous
//
#include <hip/hip_runtime.h>
#include <math.h>

#define N_NODES 100000
#define N_EDGES 1600000
#define E_TOT   1700000   // edges + self loops
#define NEG_SLOPE 0.2f
#define NBUCK 196         // ceil(100000/512) coarse buckets (dst>>9)
#define G1_BLOCKS 1563    // ceil(100000/64)
#define SCAT_BLOCKS 831   // ceil(1700000/2048)

typedef unsigned short ushort_t;
typedef unsigned int uint_t;
typedef __attribute__((ext_vector_type(8))) short bf16x8;
typedef __attribute__((ext_vector_type(4))) float f32x4;

__device__ __forceinline__ float lrelu(float v) { return v > 0.f ? v : NEG_SLOPE * v; }
__device__ __forceinline__ float bf16lo(uint_t u) { return __uint_as_float(u << 16); }
__device__ __forceinline__ float bf16hi(uint_t u) { return __uint_as_float(u & 0xffff0000u); }
// f32 -> bf16 round-to-nearest-even
__device__ __forceinline__ ushort_t f2bf(float f) {
    uint_t u = __float_as_uint(f);
    u += 0x7fffu + ((u >> 16) & 1u);
    return (ushort_t)(u >> 16);
}

union BU { uint4 u; bf16x8 b; };

// ---------------- coarse bucket histogram (runs first; feeds scanB) ----------------
__global__ __launch_bounds__(256) void k_histC(const int* __restrict__ ei,
                                               int* __restrict__ bucket_cnt)
{
    __shared__ int lbin[NBUCK];
    const int t = threadIdx.x;
    const int e0 = blockIdx.x * 2048 + t;
    for (int i = t; i < NBUCK; i += 256) lbin[i] = 0;
    __syncthreads();
#pragma unroll
    for (int i = 0; i < 8; ++i) {
        const int e = e0 + i * 256;
        if (e < E_TOT) {
            const int d = (e < N_EDGES) ? ei[N_EDGES + e] : (e - N_EDGES);
            atomicAdd(&lbin[d >> 9], 1);
        }
    }
    __syncthreads();
    for (int i = t; i < NBUCK; i += 256)
        if (lbin[i]) atomicAdd(&bucket_cnt[i], lbin[i]);
}

// ---------------- scanB: exclusive scan of bucket counts; init cursors ----------------
__global__ __launch_bounds__(256) void k_scanB(const int* __restrict__ bucket_cnt,
                                               int* __restrict__ bucket_base,
                                               int* __restrict__ bucket_cursor)
{
    __shared__ int s[256];
    const int t = threadIdx.x;
    const int v = (t < NBUCK) ? bucket_cnt[t] : 0;
    s[t] = v; __syncthreads();
    for (int off = 1; off < 256; off <<= 1) {
        int a = (t >= off) ? s[t - off] : 0;
        __syncthreads();
        s[t] += a;
        __syncthreads();
    }
    const int excl = s[t] - v;
    if (t < NBUCK) {
        bucket_base[t] = excl;
        bucket_cursor[t] = excl;
        if (t == NBUCK - 1) bucket_base[NBUCK] = excl + v;
    }
}

// ---------------- prep: W1 -> bf16 B-fragment layout ----------------
__global__ __launch_bounds__(256) void k_prep(const float* __restrict__ W,
                                              ushort_t* __restrict__ Wb)
{
    const int idx = blockIdx.x * 256 + threadIdx.x;   // 16384 total
    const int j  = idx & 7;
    const int kq = (idx >> 3) & 3;
    const int n  = (idx >> 5) & 15;
    const int tc = (idx >> 9) & 7;
    const int kc = idx >> 12;
    const int k = kc * 32 + kq * 8 + j;
    const int col = tc * 16 + n;
    Wb[idx] = f2bf(W[k * 128 + col]);
}

// ---------------- fused MFMA-GEMM1 (+alpha1) || scatterB ----------------
__global__ __launch_bounds__(256) void k_gemm1_scat(const float* __restrict__ x,
                                                    const ushort_t* __restrict__ Wb,
                                                    const float* __restrict__ a_src,
                                                    const float* __restrict__ a_dst,
                                                    ushort_t* __restrict__ hb,
                                                    float* __restrict__ as_,
                                                    float* __restrict__ ad_,
                                                    const int* __restrict__ ei,
                                                    int* __restrict__ bucket_cursor,
                                                    uint2* __restrict__ pairs)
{
    __shared__ int lcnt[NBUCK];
    __shared__ int lbase[NBUCK];
    const int t = threadIdx.x;

    if (blockIdx.x >= G1_BLOCKS) {
        // ---- scatter path: edges -> bucket-grouped (src,dst) pairs ----
        const int e0 = (blockIdx.x - G1_BLOCKS) * 2048 + t;
        for (int i = t; i < NBUCK; i += 256) lcnt[i] = 0;
        __syncthreads();
        int s8[8], d8[8];
#pragma unroll
        for (int i = 0; i < 8; ++i) {
            const int e = e0 + i * 256;
            int s = -1, d = 0;
            if (e < E_TOT) {
                if (e < N_EDGES) { s = ei[e]; d = ei[N_EDGES + e]; }
                else { s = d = e - N_EDGES; }
                atomicAdd(&lcnt[d >> 9], 1);
            }
            s8[i] = s; d8[i] = d;
        }
        __syncthreads();
        for (int i = t; i < NBUCK; i += 256) {
            const int c = lcnt[i];
            lbase[i] = (c > 0) ? atomicAdd(&bucket_cursor[i], c) : 0;
        }
        __syncthreads();
        for (int i = t; i < NBUCK; i += 256) lcnt[i] = 0;   // reuse as local cursor
        __syncthreads();
#pragma unroll
        for (int i = 0; i < 8; ++i) {
            if (s8[i] >= 0) {
                const int b = d8[i] >> 9;
                const int pos = lbase[b] + atomicAdd(&lcnt[b], 1);
                pairs[pos] = make_uint2((uint_t)s8[i], (uint_t)d8[i]);
            }
        }
        return;
    }

    // ---- gemm1 path (MFMA) ----
    const int lane = t & 63;
    const int w = t >> 6;
    const int rbase = blockIdx.x * 64 + w * 16;
    const int li = lane & 15;
    const int g = lane >> 4;

    f32x4 acc[8];
#pragma unroll
    for (int tc = 0; tc < 8; ++tc) acc[tc] = (f32x4){0.f, 0.f, 0.f, 0.f};

    int arow = rbase + li;
    if (arow > N_NODES - 1) arow = N_NODES - 1;
    const float* xr = x + (size_t)arow * 128 + g * 8;

#pragma unroll
    for (int kc = 0; kc < 4; ++kc) {
        const float4 a0 = *(const float4*)(xr + kc * 32);
        const float4 a1 = *(const float4*)(xr + kc * 32 + 4);
        BU au;
        au.u.x = (uint_t)f2bf(a0.x) | ((uint_t)f2bf(a0.y) << 16);
        au.u.y = (uint_t)f2bf(a0.z) | ((uint_t)f2bf(a0.w) << 16);
        au.u.z = (uint_t)f2bf(a1.x) | ((uint_t)f2bf(a1.y) << 16);
        au.u.w = (uint_t)f2bf(a1.z) | ((uint_t)f2bf(a1.w) << 16);
        const bf16x8 af = au.b;
#pragma unroll
        for (int tc = 0; tc < 8; ++tc) {
            const bf16x8 bf = *(const bf16x8*)(Wb + (size_t)(kc * 8 + tc) * 512 + li * 32 + g * 8);
            acc[tc] = __builtin_amdgcn_mfma_f32_16x16x32_bf16(af, bf, acc[tc], 0, 0, 0);
        }
    }

#pragma unroll
    for (int r = 0; r < 4; ++r) {
        const int row = rbase + g * 4 + r;
        if (row < N_NODES) {
            ushort_t* hp = hb + (size_t)row * 128 + li;
#pragma unroll
            for (int tc = 0; tc < 8; ++tc) hp[tc * 16] = f2bf(acc[tc][r]);
        }
    }

    float asv[8], adv[8];
#pragma unroll
    for (int tc = 0; tc < 8; ++tc) {
        asv[tc] = a_src[tc * 16 + li];
        adv[tc] = a_dst[tc * 16 + li];
    }
#pragma unroll
    for (int h = 0; h < 4; ++h) {
#pragma unroll
        for (int r = 0; r < 4; ++r) {
            float ps = acc[2 * h][r] * asv[2 * h] + acc[2 * h + 1][r] * asv[2 * h + 1];
            float pd = acc[2 * h][r] * adv[2 * h] + acc[2 * h + 1][r] * adv[2 * h + 1];
            ps += __shfl_xor(ps, 1); pd += __shfl_xor(pd, 1);
            ps += __shfl_xor(ps, 2); pd += __shfl_xor(pd, 2);
            ps += __shfl_xor(ps, 4); pd += __shfl_xor(pd, 4);
            ps += __shfl_xor(ps, 8); pd += __shfl_xor(pd, 8);
            const int row = rbase + g * 4 + r;
            if (li == 0 && row < N_NODES) {
                as_[row * 4 + h] = ps;
                ad_[row * 4 + h] = pd;
            }
        }
    }
}

// ---------------- buildC: per-bucket fine sort -> row_ptr + col_src ----------------
__global__ __launch_bounds__(256) void k_buildC(const uint2* __restrict__ pairs,
                                                const int* __restrict__ bucket_base,
                                                int* __restrict__ row_ptr,
                                                int* __restrict__ col_src)
{
    __shared__ int cnt[512];
    __shared__ int cur[512];
    __shared__ int ps[256];
    const int b = blockIdx.x, t = threadIdx.x;
    const int bstart = bucket_base[b], bend = bucket_base[b + 1];
    const int node0 = b << 9;

    cnt[t] = 0; cnt[t + 256] = 0;
    __syncthreads();
    for (int e = bstart + t; e < bend; e += 256)
        atomicAdd(&cnt[pairs[e].y - node0], 1);
    __syncthreads();

    const int pa = cnt[2 * t], pb = cnt[2 * t + 1];
    ps[t] = pa + pb; __syncthreads();
    for (int off = 1; off < 256; off <<= 1) {
        int a = (t >= off) ? ps[t - off] : 0;
        __syncthreads();
        ps[t] += a;
        __syncthreads();
    }
    const int pe = bstart + ps[t] - (pa + pb);
    cur[2 * t] = pe;
    cur[2 * t + 1] = pe + pa;
    const int n0 = node0 + 2 * t, n1 = node0 + 2 * t + 1;
    if (n0 < N_NODES) row_ptr[n0] = pe;
    if (n1 < N_NODES) row_ptr[n1] = pe + pa;
    if (b == 0 && t == 0) row_ptr[N_NODES] = E_TOT;
    __syncthreads();

    for (int e = bstart + t; e < bend; e += 256) {
        const uint2 pr = pairs[e];
        const int pos = atomicAdd(&cur[pr.y - node0], 1);
        col_src[pos] = (int)pr.x;
    }
}

// ---------------- agg1: 4 ch/lane, 2-way edge split -> x2[N,128] bf16 ----------------
__global__ __launch_bounds__(64) void k_agg1(const ushort_t* __restrict__ hb,
                                             const float* __restrict__ as_,
                                             const float* __restrict__ ad_,
                                             const int* __restrict__ row_ptr,
                                             const int* __restrict__ col_src,
                                             const float* __restrict__ bias,
                                             ushort_t* __restrict__ x2b)
{
    __shared__ float sEx[256];
    __shared__ int sSrc[64];
    const int n = blockIdx.x;
    const int lane = threadIdx.x;
    const int start = row_ptr[n], end = row_ptr[n + 1];
    const float4 adv = *(const float4*)(ad_ + (size_t)n * 4);

    const int half = lane >> 5;
    const int cg = lane & 31;
    const int c4 = cg * 4;          // 4 channels per lane
    const int head = cg >> 3;

    float4 acc = make_float4(0.f, 0.f, 0.f, 0.f);
    float4 ds = make_float4(0.f, 0.f, 0.f, 0.f);
    for (int base = start; base < end; base += 64) {
        const int e = base + lane;
        const int cnt = min(64, end - base);
        float4 ex = make_float4(0.f, 0.f, 0.f, 0.f);
        int s = 0;
        if (e < end) {
            s = col_src[e];
            const float4 av = *(const float4*)(as_ + (size_t)s * 4);
            ex.x = __expf(lrelu(av.x + adv.x));
            ex.y = __expf(lrelu(av.y + adv.y));
            ex.z = __expf(lrelu(av.z + adv.z));
            ex.w = __expf(lrelu(av.w + adv.w));
            ds.x += ex.x; ds.y += ex.y; ds.z += ex.z; ds.w += ex.w;
        }
        __syncthreads();
        *(float4*)(sEx + lane * 4) = ex;
        sSrc[lane] = s;
        __syncthreads();
        for (int i = half; i < cnt; i += 2) {
            const float w = sEx[i * 4 + head];
            const uint2 hv = *(const uint2*)(hb + (size_t)sSrc[i] * 128 + c4);
            acc.x = fmaf(w, bf16lo(hv.x), acc.x);
            acc.y = fmaf(w, bf16hi(hv.x), acc.y);
            acc.z = fmaf(w, bf16lo(hv.y), acc.z);
            acc.w = fmaf(w, bf16hi(hv.y), acc.w);
        }
    }
#pragma unroll
    for (int off = 32; off > 0; off >>= 1) {
        ds.x += __shfl_xor(ds.x, off);
        ds.y += __shfl_xor(ds.y, off);
        ds.z += __shfl_xor(ds.z, off);
        ds.w += __shfl_xor(ds.w, off);
    }
    acc.x += __shfl_xor(acc.x, 32);
    acc.y += __shfl_xor(acc.y, 32);
    acc.z += __shfl_xor(acc.z, 32);
    acc.w += __shfl_xor(acc.w, 32);

    if (half == 0) {
        const float denom = head == 0 ? ds.x : head == 1 ? ds.y : head == 2 ? ds.z : ds.w;
        const float4 b4 = *(const float4*)(bias + c4);
        float o0 = acc.x / denom + b4.x;
        float o1 = acc.y / denom + b4.y;
        float o2 = acc.z / denom + b4.z;
        float o3 = acc.w / denom + b4.w;
        o0 = o0 > 0.f ? o0 : __expf(o0) - 1.f;
        o1 = o1 > 0.f ? o1 : __expf(o1) - 1.f;
        o2 = o2 > 0.f ? o2 : __expf(o2) - 1.f;
        o3 = o3 > 0.f ? o3 : __expf(o3) - 1.f;
        const uint_t q0 = f2bf(o0), q1 = f2bf(o1), q2 = f2bf(o2), q3 = f2bf(o3);
        *(uint2*)(x2b + (size_t)n * 128 + c4) = make_uint2(q0 | (q1 << 16), q2 | (q3 << 16));
    }
}

// ---------------- GEMM2: 64 rows/block, W2 staged once; fused alpha2 ----------------
__global__ __launch_bounds__(256) void k_gemm2(const ushort_t* __restrict__ x2b,
                                               const float* __restrict__ W,
                                               const float* __restrict__ a_src,
                                               const float* __restrict__ a_dst,
                                               ushort_t* __restrict__ hb2,
                                               float* __restrict__ as_,
                                               float* __restrict__ ad_)
{
    __shared__ float sW[128 * 32];
    const int t = threadIdx.x;
    {
        const float4* W4 = (const float4*)W;
        float4* s4 = (float4*)sW;
#pragma unroll
        for (int i = 0; i < 4; ++i) s4[t + 256 * i] = W4[t + 256 * i];
    }
    __syncthreads();

    const int rr = t >> 5;
    const int c = t & 31;
    const float a_s = a_src[c], a_d = a_dst[c];

    for (int g = 0; g < 8; ++g) {
        const int row = blockIdx.x * 64 + g * 8 + rr;
        if (row >= N_NODES) continue;
        const ushort_t* xp = x2b + (size_t)row * 128;

        float acc = 0.f;
        for (int k = 0; k < 128; k += 4) {
            const uint2 u = *(const uint2*)(xp + k);
            acc = fmaf(bf16lo(u.x), sW[(k + 0) * 32 + c], acc);
            acc = fmaf(bf16hi(u.x), sW[(k + 1) * 32 + c], acc);
            acc = fmaf(bf16lo(u.y), sW[(k + 2) * 32 + c], acc);
            acc = fmaf(bf16hi(u.y), sW[(k + 3) * 32 + c], acc);
        }

        hb2[(size_t)row * 32 + c] = f2bf(acc);
        float ps = acc * a_s, pd = acc * a_d;
#pragma unroll
        for (int off = 16; off > 0; off >>= 1) {
            ps += __shfl_xor(ps, off);
            pd += __shfl_xor(pd, off);
        }
        if (c == 0) { as_[row] = ps; ad_[row] = pd; }
    }
}

// ---------------- agg2: 2 ch/lane, 4-way edge split -> out[N,32] ----------------
__global__ __launch_bounds__(64) void k_agg2(const ushort_t* __restrict__ hb2,
                                             const float* __restrict__ as_,
                                             const float* __restrict__ ad_,
                                             const int* __restrict__ row_ptr,
                                             const int* __restrict__ col_src,
                                             const float* __restrict__ bias,
                                             float* __restrict__ out)
{
    __shared__ float sEx[64];
    __shared__ int sSrc[64];
    const int n = blockIdx.x;
    const int lane = threadIdx.x;
    const int start = row_ptr[n], end = row_ptr[n + 1];
    const float adn = ad_[n];

    const int quarter = lane >> 4;
    const int cg = lane & 15;
    const int c2 = cg * 2;

    float2 acc = make_float2(0.f, 0.f);
    float dsum = 0.f;
    for (int base = start; base < end; base += 64) {
        const int e = base + lane;
        const int cnt = min(64, end - base);
        float ex = 0.f; int s = 0;
        if (e < end) {
            s = col_src[e];
            ex = __expf(lrelu(as_[s] + adn));
            dsum += ex;
        }
        __syncthreads();
        sEx[lane] = ex;
        sSrc[lane] = s;
        __syncthreads();
        for (int i = quarter; i < cnt; i += 4) {
            const float w = sEx[i];
            const uint_t hv = *(const uint_t*)(hb2 + (size_t)sSrc[i] * 32 + c2);
            acc.x = fmaf(w, bf16lo(hv), acc.x);
            acc.y = fmaf(w, bf16hi(hv), acc.y);
        }
    }
#pragma unroll
    for (int off = 32; off > 0; off >>= 1) dsum += __shfl_xor(dsum, off);
    acc.x += __shfl_xor(acc.x, 16);
    acc.y += __shfl_xor(acc.y, 16);
    acc.x += __shfl_xor(acc.x, 32);
    acc.y += __shfl_xor(acc.y, 32);
    if (quarter == 0) {
        float2 o = make_float2(acc.x / dsum + bias[c2], acc.y / dsum + bias[c2 + 1]);
        *(float2*)(out + (size_t)n * 32 + c2) = o;
    }
}

extern "C" void kernel_launch(void* const* d_in, const int* in_sizes, int n_in,
                              void* d_out, int out_size, void* d_ws, size_t ws_size,
                              hipStream_t stream)
{
    const float* x      = (const float*)d_in[0];
    const int*   ei     = (const int*)d_in[1];
    const float* W1     = (const float*)d_in[2];
    const float* a_src1 = (const float*)d_in[3];
    const float* a_dst1 = (const float*)d_in[4];
    const float* b1     = (const float*)d_in[5];
    const float* W2     = (const float*)d_in[6];
    const float* a_src2 = (const float*)d_in[7];
    const float* a_dst2 = (const float*)d_in[8];
    const float* b2     = (const float*)d_in[9];
    float* out = (float*)d_out;

    char* p = (char*)d_ws;
    auto alloc = [&](size_t bytes) { char* q = p; p += (bytes + 255) & ~(size_t)255; return q; };
    ushort_t* h1b = (ushort_t*)alloc((size_t)N_NODES * 128 * 2);
    ushort_t* x2b = (ushort_t*)alloc((size_t)N_NODES * 128 * 2);
    ushort_t* h2b = (ushort_t*)alloc((size_t)N_NODES * 32 * 2);
    ushort_t* Wb  = (ushort_t*)alloc((size_t)16384 * 2);
    float* as1    = (float*)alloc((size_t)N_NODES * 4 * 4);
    float* ad1    = (float*)alloc((size_t)N_NODES * 4 * 4);
    float* as2    = (float*)alloc((size_t)N_NODES * 4);
    float* ad2    = (float*)alloc((size_t)N_NODES * 4);
    int* row_ptr  = (int*)alloc((size_t)(N_NODES + 1) * 4);
    int* bucket_cnt    = (int*)alloc((NBUCK + 1) * 4);
    int* bucket_base   = (int*)alloc((NBUCK + 1) * 4);
    int* bucket_cursor = (int*)alloc((NBUCK + 1) * 4);
    uint2* pairs  = (uint2*)alloc((size_t)E_TOT * 8);
    int* col_src  = (int*)alloc((size_t)E_TOT * 4);

    (void)hipMemsetAsync(bucket_cnt, 0, (NBUCK + 1) * 4, stream);

    k_histC<<<SCAT_BLOCKS, 256, 0, stream>>>(ei, bucket_cnt);
    k_scanB<<<1, 256, 0, stream>>>(bucket_cnt, bucket_base, bucket_cursor);
    k_prep<<<64, 256, 0, stream>>>(W1, Wb);
    k_gemm1_scat<<<G1_BLOCKS + SCAT_BLOCKS, 256, 0, stream>>>(
        x, Wb, a_src1, a_dst1, h1b, as1, ad1, ei, bucket_cursor, pairs);
    k_buildC<<<NBUCK, 256, 0, stream>>>(pairs, bucket_base, row_ptr, col_src);
    k_agg1<<<N_NODES, 64, 0, stream>>>(h1b, as1, ad1, row_ptr, col_src, b1, x2b);
    k_gemm2<<<(N_NODES + 63) / 64, 256, 0, stream>>>(x2b, W2, a_src2, a_dst2, h2b, as2, ad2);
    k_agg2<<<N_NODES, 64, 0, stream>>>(h2b, as2, ad2, row_ptr, col_src, b2, out);
}